// Round 11
// baseline (398.471 us; speedup 1.0000x reference)
//
#include <hip/hip_runtime.h>
#include <hip/hip_bf16.h>

typedef unsigned short u16;
typedef unsigned int u32;
typedef __attribute__((ext_vector_type(4))) float f32x4;
typedef __attribute__((ext_vector_type(8))) short s16x8;
typedef __attribute__((ext_vector_type(8))) unsigned short u16x8;
typedef __attribute__((ext_vector_type(4))) unsigned short u16x4;

#define EPS_V (1e-10f)

__device__ __forceinline__ u16 f2bf(float f) {   // RNE
  unsigned u = __float_as_uint(f);
  u += 0x7fffu + ((u >> 16) & 1u);
  return (u16)(u >> 16);
}
__device__ __forceinline__ float bf2f(u16 h) {
  return __uint_as_float(((unsigned)h) << 16);
}
__device__ __forceinline__ float wred_sum(float v) {
#pragma unroll
  for (int o = 32; o; o >>= 1) v += __shfl_xor(v, o);
  return v;
}
__device__ __forceinline__ float red16(float v) {   // sum within 16-lane group
  v += __shfl_xor(v, 1); v += __shfl_xor(v, 2);
  v += __shfl_xor(v, 4); v += __shfl_xor(v, 8);
  return v;
}
__device__ __forceinline__ bool mask_at(const void* m, int kind, int idx) {
  if (kind == 0) return ((const int*)m)[idx] != 0;
  if (kind == 1) return ((const float*)m)[idx] != 0.0f;
  return ((const unsigned char*)m)[idx] != 0;
}

// ---------- K0: b0 = mask-detect, b1..320 = pack, rest = zero accumulators ----------
__global__ __launch_bounds__(256) void k0_fused(
    const unsigned int* __restrict__ mask_raw,
    const float* __restrict__ w_node, const float* __restrict__ W_agn,
    const float* __restrict__ W_nga, const float* __restrict__ W_qna,
    const float* __restrict__ W_qan,
    int* __restrict__ mkind, u16* __restrict__ Wpack,
    float* __restrict__ zero_base, int nzero, int ndw) {
  const int b = blockIdx.x;
  const int t = threadIdx.x;
  if (b == 0) {
    __shared__ int notInt, notFloat;
    if (t == 0) { notInt = 0; notFloat = 0; }
    __syncthreads();
    int li = 0, lf = 0;
    for (int i = t; i < ndw; i += 256) {
      unsigned v = mask_raw[i];
      if (v != 0u && v != 1u) li = 1;
      if (v != 0u && v != 0x3F800000u) lf = 1;
    }
    if (li) atomicOr(&notInt, 1);
    if (lf) atomicOr(&notFloat, 1);
    __syncthreads();
    if (t == 0) mkind[0] = (!notInt) ? 0 : ((!notFloat) ? 1 : 2);
  } else if (b <= 320) {
    int idx = (b - 1) * 256 + t;   // < 320*256
    int col = idx >> 8, k = idx & 255;
    float v = 0.f;
    if (col < 64) v = W_agn[col * 256 + k];
    else if (col < 128) v = W_nga[(col - 64) * 256 + k];
    else if (col < 192) v = W_qna[(col - 128) * 256 + k];
    else if (col < 256) v = W_qan[(col - 192) * 256 + k];
    else if (col == 256) v = w_node[k];
    Wpack[idx] = f2bf(v);
  } else {
    int idx = (b - 321) * 256 + t;
    if (idx < nzero) zero_base[idx] = 0.f;
  }
}

// fragment: 8 bf16 of LDS-row m (f32 data), k=k0..k0+7, 16B-granule XOR-(m&7)
__device__ __forceinline__ s16x8 frag_from_lds(const float* Vf, int m, int k0) {
  int g0 = ((k0 >> 2) ^ (m & 7));
  int g1 = g0 ^ 1;
  const f32x4 lo = *reinterpret_cast<const f32x4*>(&Vf[m * 256 + g0 * 4]);
  const f32x4 hi = *reinterpret_cast<const f32x4*>(&Vf[m * 256 + g1 * 4]);
  union { s16x8 v; u32 u[4]; } r;
  r.u[0] = __builtin_amdgcn_perm(__float_as_uint(lo[1]), __float_as_uint(lo[0]), 0x07060302u);
  r.u[1] = __builtin_amdgcn_perm(__float_as_uint(lo[3]), __float_as_uint(lo[2]), 0x07060302u);
  r.u[2] = __builtin_amdgcn_perm(__float_as_uint(hi[1]), __float_as_uint(hi[0]), 0x07060302u);
  r.u[3] = __builtin_amdgcn_perm(__float_as_uint(hi[3]), __float_as_uint(hi[2]), 0x07060302u);
  return r.v;
}

// ---------- K1 fused: wave-owns-rows GEMM + per-node reductions.
// 2048 blocks x 256 thr (4 waves). Block = 64 rows; wave w owns rows w*16..+15
// and ALL 17 col-frags (agn|nga|qna|qan|nl). R5-style single-barrier staging
// (gload_lds f32, 64KB). Epilogue: in-wave row-softmax (red16), run-length
// register accumulators -> end-of-run atomics (pa_un,S,V,I,q_a,Sn).
// Stores: only nga (bf16, coalesced via outbuf). ----------
__global__ __launch_bounds__(256) void k1_fused(
    const float* __restrict__ values, const u16* __restrict__ Wpack,
    const int* __restrict__ indices, const void* __restrict__ mask,
    const int* __restrict__ mkind,
    const float* __restrict__ b_agn, const float* __restrict__ b_nga,
    const float* __restrict__ b_qna, const float* __restrict__ b_qan,
    u16* __restrict__ nga_bf, float* __restrict__ nga_f32,
    float* __restrict__ pa_un, float* __restrict__ S_at,
    float* __restrict__ V_at, float* __restrict__ I_at,
    float* __restrict__ q_a, float* __restrict__ Sn_at, int nga_is_bf) {
  __shared__ float Vf[64 * 256];      // 64 KB f32 tile
  __shared__ u16 outbuf[4][16][68];   // per-wave nga staging (conflict-padded)
  __shared__ int segid[64];

  const int t = threadIdx.x;
  const int lane = t & 63;
  const int wave = t >> 6;
  const int l15 = lane & 15;
  const int kg = lane >> 4;           // = lane-group q
  const int blk0 = blockIdx.x * 64;
  const int kind = mkind[0];

  if (t < 64) segid[t] = indices[blk0 + t];

  // stage 16 rows per wave (source granule-swizzled, dest linear) [R5-verified]
#pragma unroll
  for (int i = 0; i < 16; ++i) {
    int m = wave * 16 + i;
    const float* gp = values + (size_t)(blk0 + m) * 256 + ((lane ^ (m & 7)) << 2);
    __builtin_amdgcn_global_load_lds((const __attribute__((address_space(1))) void*)gp,
        (__attribute__((address_space(3))) void*)&Vf[m * 256], 16, 0, 0);
  }

  // per-lane biases for 16 col-frags (frag 16 = nl, bias 0)
  float bias_all[17];
#pragma unroll
  for (int cg = 0; cg < 16; ++cg) {
    const float* bp = (cg < 4) ? b_agn : (cg < 8) ? b_nga : (cg < 12) ? b_qna : b_qan;
    bias_all[cg] = bp[(cg & 3) * 16 + l15];
  }
  bias_all[16] = 0.f;

  __syncthreads();   // the only barrier (drains gload_lds)

  f32x4 acc[17];
#pragma unroll
  for (int cg = 0; cg < 17; ++cg) acc[cg] = (f32x4){0.f, 0.f, 0.f, 0.f};

  const u16* wb = Wpack + (size_t)l15 * 256 + kg * 8;
#pragma unroll 2
  for (int s = 0; s < 8; ++s) {
    s16x8 a = frag_from_lds(Vf, wave * 16 + l15, s * 32 + kg * 8);
#pragma unroll
    for (int cg = 0; cg < 17; ++cg) {
      s16x8 b = *reinterpret_cast<const s16x8*>(wb + (size_t)cg * 4096 + s * 32);
      acc[cg] = __builtin_amdgcn_mfma_f32_16x16x32_bf16(a, b, acc[cg], 0, 0, 0);
    }
  }

  // ---- epilogue: C/D map col = lane&15, row = (lane>>4)*4 + reg [m89/m91] ----
  // lane-group kg handles nodes (wave*16 + kg*4 + r), r = reg 0..3.
  const int rw0 = wave * 16;
  float pa_[4] = {0.f, 0.f, 0.f, 0.f}, Ss_[4] = {0.f, 0.f, 0.f, 0.f};
  float Vv_[4] = {0.f, 0.f, 0.f, 0.f}, Ii_[4] = {0.f, 0.f, 0.f, 0.f};
  float Qq_[4] = {0.f, 0.f, 0.f, 0.f};
  float sn_ = 0.f;
  int cur_g = segid[rw0 + kg * 4];
  bool mv[4];
#pragma unroll
  for (int cg = 0; cg < 4; ++cg) mv[cg] = mask_at(mask, kind, cur_g * 64 + cg * 16 + l15);

#define FLUSH()                                                       \
  {                                                                   \
    _Pragma("unroll")                                                 \
    for (int cg_ = 0; cg_ < 4; ++cg_) {                               \
      int a_ = cur_g * 64 + cg_ * 16 + l15;                           \
      atomicAdd(&pa_un[a_], pa_[cg_]);                                \
      atomicAdd(&S_at[a_], Ss_[cg_]);                                 \
      atomicAdd(&V_at[a_], Vv_[cg_]);                                 \
      atomicAdd(&I_at[a_], Ii_[cg_]);                                 \
      atomicAdd(&q_a[a_], Qq_[cg_]);                                  \
      pa_[cg_] = Ss_[cg_] = Vv_[cg_] = Ii_[cg_] = Qq_[cg_] = 0.f;     \
    }                                                                 \
    if (l15 == 0) { atomicAdd(&Sn_at[cur_g], sn_); sn_ = 0.f; }       \
  }

#pragma unroll
  for (int r = 0; r < 4; ++r) {
    int m = kg * 4 + r;                 // row within wave's 16
    int g = segid[rw0 + m];
    if (g != cur_g) {                   // uniform within 16-lane group
      FLUSH();
      cur_g = g;
#pragma unroll
      for (int cg = 0; cg < 4; ++cg) mv[cg] = mask_at(mask, kind, g * 64 + cg * 16 + l15);
    }
    // node logit (frag 16, col 0 real at l15==0; cols 1-15 are zero weights)
    float ex = __expf(acc[16][r]);
    float pn_e = __shfl(ex, kg * 16);   // broadcast group's l15==0 value
    sn_ += pn_e;                        // flushed only from l15==0 lanes
    // p(a|n): masked row softmax over 64 agn cols (frags 0-3)
    float e[4];
    float rs = 0.f;
#pragma unroll
    for (int cg = 0; cg < 4; ++cg) {
      e[cg] = mv[cg] ? __expf(acc[cg][r] + bias_all[cg]) : 0.f;
      rs += e[cg];
    }
    rs = red16(rs);
    if (rs > 0.f) {
      float invp = pn_e / rs;
#pragma unroll
      for (int cg = 0; cg < 4; ++cg) pa_[cg] += e[cg] * invp;
    } else {
#pragma unroll
      for (int cg = 0; cg < 4; ++cg) pa_[cg] += pn_e * 0.015625f;
    }
    // nga stats + store (frags 4-7), qna dot (8-11), qan sum (12-15)
#pragma unroll
    for (int cg = 0; cg < 4; ++cg) {
      float y = acc[4 + cg][r] + bias_all[4 + cg];
      float ey = __expf(y);
      Ss_[cg] += ey;
      Vv_[cg] += ey * y;
      Ii_[cg] += ey * (acc[8 + cg][r] + bias_all[8 + cg]);
      Qq_[cg] += acc[12 + cg][r] + bias_all[12 + cg];
      if (nga_is_bf) outbuf[wave][m][cg * 16 + l15] = f2bf(y);
      else nga_f32[(size_t)(blk0 + rw0 + m) * 64 + cg * 16 + l15] = y;
    }
  }
  FLUSH();
#undef FLUSH

  // coalesced nga store: 4 x 512B per wave (wave-local outbuf, no barrier)
  if (nga_is_bf) {
#pragma unroll
    for (int j = 0; j < 4; ++j) {
      int li = lane + j * 64;
      int rr = li >> 4, cc = (li & 15) * 4;
      u16x4 v = *reinterpret_cast<const u16x4*>(&outbuf[wave][rr][cc]);
      *reinterpret_cast<u16x4*>(nga_bf + (size_t)(blk0 + rw0) * 64 + (size_t)li * 4) = v;
    }
  }
}

// ---------- K2 finalize: per (g,a) -> p_a, entropy, value (R7-verified math) ----------
__global__ __launch_bounds__(64) void k2_finalize(
    const float* __restrict__ pa_un, const float* __restrict__ S_at,
    const float* __restrict__ V_at, const float* __restrict__ I_at,
    const float* __restrict__ q_a, const float* __restrict__ Sn_at,
    const int* __restrict__ n_nodes, const void* __restrict__ mask,
    const int* __restrict__ mkind,
    float* __restrict__ p_a, float* __restrict__ entropy, float* __restrict__ value) {
  const int g = blockIdx.x;
  const int a = threadIdx.x;   // 64
  float Sn = Sn_at[g];
  float P = (Sn > 0.f) ? pa_un[g * 64 + a] / Sn : 0.f;
  float S = S_at[g * 64 + a];
  float V = V_at[g * 64 + a];
  float I = I_at[g * 64 + a];
  float q = q_a[g * 64 + a];
  int n = n_nodes[g];
  bool mva = mask_at(mask, mkind[0], g * 64 + a);
  float Hn;
  if (n <= 0) Hn = 0.f;
  else if (!mva) Hn = -logf(1.0f / (float)n + EPS_V);
  else Hn = (S > 0.f) ? (logf(S) - V / S) : 0.f;
  float inner = (S > 0.f) ? I / S : 0.f;
  float ent = -P * logf(P + EPS_V) + P * Hn;
  float val = P * (q + inner);
  p_a[g * 64 + a] = P;
  ent = wred_sum(ent);
  val = wred_sum(val);
  if (a == 0) { entropy[g] = ent; value[g] = val; }
}

// ---------- K3: logprob ----------
__global__ __launch_bounds__(256) void k3_logprob(
    const float* __restrict__ p_a, const u16* __restrict__ nga_bf,
    const float* __restrict__ nga_f32, const int* __restrict__ indices,
    const int* __restrict__ a_action, const int* __restrict__ a_node,
    const void* __restrict__ mask, const int* __restrict__ mkind,
    const int* __restrict__ n_nodes, const float* __restrict__ Su,
    float* __restrict__ logprob, int G, int nga_is_bf) {
  int g = blockIdx.x * blockDim.x + threadIdx.x;
  if (g >= G) return;
  int kind = mkind[0];
  int a = a_action[g];
  float t1 = logf(p_a[g * 64 + a] + EPS_V);
  int node = a_node[g];
  int g2 = indices[node];
  float p2;
  if (mask_at(mask, kind, g2 * 64 + a)) {
    float S = Su[g2 * 64 + a];
    float y = nga_is_bf ? bf2f(nga_bf[(size_t)node * 64 + a]) : nga_f32[(size_t)node * 64 + a];
    p2 = (S > 0.f) ? __expf(y) / S : 0.f;
  } else {
    p2 = 1.0f / (float)n_nodes[g2];
  }
  logprob[g] = t1 + logf(p2 + EPS_V);
}

// ---------- K4 (bf16): p_n__a = exp(y)/Su ----------
__global__ __launch_bounds__(256) void k4_pna_bf(
    const u16* __restrict__ nga_bf, const int* __restrict__ indices,
    const float* __restrict__ Su, float* __restrict__ pna, int N) {
  int e8 = blockIdx.x * 256 + threadIdx.x;
  if (e8 >= N * 8) return;
  int i = e8 >> 3, a0 = (e8 & 7) * 8;
  int g = indices[i];
  u16x8 y = *reinterpret_cast<const u16x8*>(nga_bf + (size_t)i * 64 + a0);
  float4 S0 = *reinterpret_cast<const float4*>(Su + g * 64 + a0);
  float4 S1 = *reinterpret_cast<const float4*>(Su + g * 64 + a0 + 4);
  float4 o0, o1;
  o0.x = __expf(bf2f(y[0])) / S0.x; o0.y = __expf(bf2f(y[1])) / S0.y;
  o0.z = __expf(bf2f(y[2])) / S0.z; o0.w = __expf(bf2f(y[3])) / S0.w;
  o1.x = __expf(bf2f(y[4])) / S1.x; o1.y = __expf(bf2f(y[5])) / S1.y;
  o1.z = __expf(bf2f(y[6])) / S1.z; o1.w = __expf(bf2f(y[7])) / S1.w;
  float4* dst = reinterpret_cast<float4*>(pna + (size_t)i * 64 + a0);
  dst[0] = o0; dst[1] = o1;
}

// ---------- K4 (f32 fallback, in-place) ----------
__global__ __launch_bounds__(256) void k4_pna_f32(
    float* __restrict__ pna, const int* __restrict__ indices,
    const float* __restrict__ Su, int N) {
  int e4 = blockIdx.x * 256 + threadIdx.x;
  if (e4 >= N * 16) return;
  int i = e4 >> 4, a0 = (e4 & 15) * 4;
  int g = indices[i];
  float4* p = reinterpret_cast<float4*>(pna + (size_t)i * 64 + a0);
  float4 x = *p;
  float4 S = *reinterpret_cast<const float4*>(Su + g * 64 + a0);
  float4 o;
  o.x = __expf(x.x) / S.x; o.y = __expf(x.y) / S.y;
  o.z = __expf(x.z) / S.z; o.w = __expf(x.w) / S.w;
  *p = o;
}

extern "C" void kernel_launch(void* const* d_in, const int* in_sizes, int n_in,
                              void* d_out, int out_size, void* d_ws, size_t ws_size,
                              hipStream_t stream) {
  const float* values = (const float*)d_in[0];
  const int* indices = (const int*)d_in[1];
  const int* a_action = (const int*)d_in[2];
  const int* a_node = (const int*)d_in[3];
  const void* action_mask = d_in[4];
  const int* n_nodes = (const int*)d_in[5];
  const float* w_node = (const float*)d_in[6];
  const float* W_agn = (const float*)d_in[7];
  const float* b_agn = (const float*)d_in[8];
  const float* W_nga = (const float*)d_in[9];
  const float* b_nga = (const float*)d_in[10];
  const float* W_qna = (const float*)d_in[11];
  const float* b_qna = (const float*)d_in[12];
  const float* W_qan = (const float*)d_in[13];
  const float* b_qan = (const float*)d_in[14];

  const int N = in_sizes[1];   // 131072
  const int G = in_sizes[2];   // 256
  const int GA = in_sizes[4];  // G*64

  float* out = (float*)d_out;
  float* o_logprob = out;
  float* o_entropy = out + G;
  float* o_value = out + 2 * G;
  float* o_pa = out + 3 * G;
  float* o_pna = out + 3 * G + GA;

  char* w = (char*)d_ws;
  size_t off = 0;
  u16* nga_bf_pre = (u16*)(w + off); off += (size_t)N * 64 * 2;
  float* zero_base = (float*)(w + off);
  float* pa_un = (float*)(w + off); off += (size_t)GA * 4;
  float* S_at = (float*)(w + off); off += (size_t)GA * 4;
  float* V_at = (float*)(w + off); off += (size_t)GA * 4;
  float* I_at = (float*)(w + off); off += (size_t)GA * 4;
  float* q_a = (float*)(w + off); off += (size_t)GA * 4;
  float* Sn_at = (float*)(w + off); off += (size_t)G * 4;
  int nzero = 5 * GA + G;
  int* mkind = (int*)(w + off); off += 256;
  off = (off + 255) & ~(size_t)255;
  u16* Wpack = (u16*)(w + off); off += (size_t)320 * 256 * 2;
  int nga_is_bf = (ws_size >= off) ? 1 : 0;
  u16* nga_bf = nga_bf_pre;
  float* nga_f32 = o_pna;   // fallback: f32 logits in d_out, k4 in-place

  int zero_blocks = (nzero + 255) / 256;
  k0_fused<<<1 + 320 + zero_blocks, 256, 0, stream>>>(
      (const unsigned int*)action_mask, w_node, W_agn, W_nga, W_qna, W_qan,
      mkind, Wpack, zero_base, nzero, GA / 4);
  k1_fused<<<N / 64, 256, 0, stream>>>(
      values, Wpack, indices, action_mask, mkind,
      b_agn, b_nga, b_qna, b_qan,
      nga_bf, nga_f32, pa_un, S_at, V_at, I_at, q_a, Sn_at, nga_is_bf);
  k2_finalize<<<G, 64, 0, stream>>>(
      pa_un, S_at, V_at, I_at, q_a, Sn_at, n_nodes, action_mask, mkind,
      o_pa, o_entropy, o_value);
  k3_logprob<<<(G + 255) / 256, 256, 0, stream>>>(
      o_pa, nga_bf, nga_f32, indices, a_action, a_node,
      action_mask, mkind, n_nodes, S_at, o_logprob, G, nga_is_bf);
  if (nga_is_bf)
    k4_pna_bf<<<(N * 8 + 255) / 256, 256, 0, stream>>>(nga_bf, indices, S_at, o_pna, N);
  else
    k4_pna_f32<<<(N * 16 + 255) / 256, 256, 0, stream>>>(o_pna, indices, S_at, N);
}

// Round 12
// 244.231 us; speedup vs baseline: 1.6315x; 1.6315x over previous
//
#include <hip/hip_runtime.h>
#include <hip/hip_bf16.h>

typedef unsigned short u16;
typedef unsigned int u32;
typedef __attribute__((ext_vector_type(4))) float f32x4;
typedef __attribute__((ext_vector_type(8))) short s16x8;
typedef __attribute__((ext_vector_type(8))) unsigned short u16x8;
typedef __attribute__((ext_vector_type(4))) unsigned short u16x4;

#define EPS_V (1e-10f)
#define NHALF 8                 // 8 halves x 16 rows = 128 rows per block

__device__ __forceinline__ u16 f2bf(float f) {   // RNE
  unsigned u = __float_as_uint(f);
  u += 0x7fffu + ((u >> 16) & 1u);
  return (u16)(u >> 16);
}
__device__ __forceinline__ float bf2f(u16 h) {
  return __uint_as_float(((unsigned)h) << 16);
}
__device__ __forceinline__ float wred_sum(float v) {
#pragma unroll
  for (int o = 32; o; o >>= 1) v += __shfl_xor(v, o);
  return v;
}
__device__ __forceinline__ bool mask_at(const void* m, int kind, int idx) {
  if (kind == 0) return ((const int*)m)[idx] != 0;
  if (kind == 1) return ((const float*)m)[idx] != 0.0f;
  return ((const unsigned char*)m)[idx] != 0;
}

// ---------- K0 fused prologue (unchanged) ----------
__global__ __launch_bounds__(256) void k0_fused(
    const int* __restrict__ n_nodes, const unsigned int* __restrict__ mask_raw,
    const float* __restrict__ w_node, const float* __restrict__ W_agn,
    const float* __restrict__ W_nga, const float* __restrict__ W_qna,
    const float* __restrict__ W_qan,
    int* __restrict__ seg_start, int* __restrict__ mkind,
    float* __restrict__ q_a, u16* __restrict__ Wpack, int G, int ndw) {
  const int b = blockIdx.x;
  const int t = threadIdx.x;
  if (b == 0) {
    if (t < 64) {
      int base = t * 4;
      int v0 = (base + 0 < G) ? n_nodes[base + 0] : 0;
      int v1 = (base + 1 < G) ? n_nodes[base + 1] : 0;
      int v2 = (base + 2 < G) ? n_nodes[base + 2] : 0;
      int v3 = (base + 3 < G) ? n_nodes[base + 3] : 0;
      int lsum = v0 + v1 + v2 + v3;
      int x = lsum;
#pragma unroll
      for (int o = 1; o < 64; o <<= 1) {
        int y = __shfl_up(x, o);
        if (t >= o) x += y;
      }
      int run = x - lsum;
      if (base + 0 < G) seg_start[base + 0] = run; run += v0;
      if (base + 1 < G) seg_start[base + 1] = run; run += v1;
      if (base + 2 < G) seg_start[base + 2] = run; run += v2;
      if (base + 3 < G) seg_start[base + 3] = run; run += v3;
      if (t == 63) seg_start[G] = run;
    }
  } else if (b == 1) {
    __shared__ int notInt, notFloat;
    if (t == 0) { notInt = 0; notFloat = 0; }
    __syncthreads();
    int li = 0, lf = 0;
    for (int i = t; i < ndw; i += 256) {
      unsigned v = mask_raw[i];
      if (v != 0u && v != 1u) li = 1;
      if (v != 0u && v != 0x3F800000u) lf = 1;
    }
    if (li) atomicOr(&notInt, 1);
    if (lf) atomicOr(&notFloat, 1);
    __syncthreads();
    if (t == 0) mkind[0] = (!notInt) ? 0 : ((!notFloat) ? 1 : 2);
  } else if (b < 2 + 320) {
    int idx = (b - 2) * 256 + t;
    int col = idx >> 8, k = idx & 255;
    float v = 0.f;
    if (col < 64) v = W_agn[col * 256 + k];
    else if (col < 128) v = W_nga[(col - 64) * 256 + k];
    else if (col < 192) v = W_qna[(col - 128) * 256 + k];
    else if (col < 256) v = W_qan[(col - 192) * 256 + k];
    else if (col == 256) v = w_node[k];
    Wpack[idx] = f2bf(v);
  } else {
    int idx = (b - 322) * 256 + t;
    if (idx < G * 64) q_a[idx] = 0.f;
  }
}

// fragment: 8 bf16 of LDS-row m (f32 data), k=k0..k0+7, 16B-granule XOR-(m&7)
__device__ __forceinline__ s16x8 frag_from_lds(const float* Vf, int m, int k0) {
  int g0 = ((k0 >> 2) ^ (m & 7));
  int g1 = g0 ^ 1;
  const f32x4 lo = *reinterpret_cast<const f32x4*>(&Vf[m * 256 + g0 * 4]);
  const f32x4 hi = *reinterpret_cast<const f32x4*>(&Vf[m * 256 + g1 * 4]);
  union { s16x8 v; u32 u[4]; } r;
  r.u[0] = __builtin_amdgcn_perm(__float_as_uint(lo[1]), __float_as_uint(lo[0]), 0x07060302u);
  r.u[1] = __builtin_amdgcn_perm(__float_as_uint(lo[3]), __float_as_uint(lo[2]), 0x07060302u);
  r.u[2] = __builtin_amdgcn_perm(__float_as_uint(hi[1]), __float_as_uint(hi[0]), 0x07060302u);
  r.u[3] = __builtin_amdgcn_perm(__float_as_uint(hi[3]), __float_as_uint(hi[2]), 0x07060302u);
  return r.v;
}

// ---------- K1: ring-pipelined GEMM, 16-row halves, 39.4 KB LDS.
// grid 1024 (4 blocks/CU available), __launch_bounds__(256,3) -> 3 resident.
// 2-deep ring; STAGE after barrier; counted vmcnt keeps stores(h-1) in flight.
__global__ __launch_bounds__(256, 3) void k1_gemm(
    const float* __restrict__ values, const u16* __restrict__ Wpack,
    const int* __restrict__ indices,
    const float* __restrict__ b_agn, const float* __restrict__ b_nga,
    const float* __restrict__ b_qna, const float* __restrict__ b_qan,
    u16* __restrict__ agn, u16* __restrict__ nga_bf, float* __restrict__ nga_f32,
    u16* __restrict__ qna, float* __restrict__ q_a,
    float* __restrict__ nl, int nga_is_bf) {
  __shared__ float ring[2][16 * 256];   // 32 KB
  __shared__ u16 outbuf[3][16][68];     // 6.4 KB, conflict-free
  __shared__ float nlbuf[16];
  __shared__ int segid[NHALF * 16];

  const int t = threadIdx.x;
  const int lane = t & 63;
  const int wave = t >> 6;              // chunk: 0 agn, 1 nga, 2 qna, 3 qan(+nl)
  const int ln15 = lane & 15;
  const int kg = lane >> 4;
  const int blk0 = blockIdx.x * (NHALF * 16);

  // B fragments for this wave's 64-col chunk (L2-hot), once per block
  s16x8 bfr[4][8];
  {
    const u16* wb = Wpack + (size_t)(wave * 64 + ln15) * 256 + kg * 8;
#pragma unroll
    for (int cg = 0; cg < 4; ++cg)
#pragma unroll
      for (int s = 0; s < 8; ++s)
        bfr[cg][s] = *reinterpret_cast<const s16x8*>(wb + (size_t)(cg * 16) * 256 + s * 32);
  }
  float bias_c[4];
  {
    const float* bp = (wave == 0) ? b_agn : (wave == 1) ? b_nga
                    : (wave == 2) ? b_qna : b_qan;
#pragma unroll
    for (int cg = 0; cg < 4; ++cg) bias_c[cg] = bp[cg * 16 + ln15];
  }
  s16x8 bn[8];
  if (wave == 3) {
    const u16* wb = Wpack + (size_t)(256 + ln15) * 256 + kg * 8;
#pragma unroll
    for (int s = 0; s < 8; ++s)
      bn[s] = *reinterpret_cast<const s16x8*>(wb + s * 32);
#pragma unroll
    for (int j = 0; j < NHALF * 16 / 64; ++j)
      segid[lane + 64 * j] = indices[blk0 + lane + 64 * j];
  }
  float qpart[4] = {0.f, 0.f, 0.f, 0.f};
  int qg = (wave == 3) ? segid[kg * 4] : 0;

#define STAGE(hh)                                                              \
  {                                                                            \
    float* dst_ = ring[(hh) & 1];                                              \
    const int r0_ = blk0 + (hh) * 16;                                          \
    _Pragma("unroll")                                                          \
    for (int i_ = 0; i_ < 4; ++i_) {                                           \
      int m_ = wave * 4 + i_;                                                  \
      const float* gp_ = values + (size_t)(r0_ + m_) * 256 + ((lane ^ (m_ & 7)) << 2); \
      __builtin_amdgcn_global_load_lds(                                        \
          (const __attribute__((address_space(1))) void*)gp_,                  \
          (__attribute__((address_space(3))) void*)&dst_[m_ * 256], 16, 0, 0); \
    }                                                                          \
  }

  STAGE(0);

  for (int h = 0; h < NHALF; ++h) {
    // wait for OWN loads(h); younger ops = stores(h-1) (waves 0-2: 4 b64;
    // wave 3: 1 nl store). h=0: only loads(0) outstanding.
    if (h == 0 || (!nga_is_bf && wave == 1)) {
      asm volatile("s_waitcnt vmcnt(0)" ::: "memory");
    } else if (wave == 3) {
      asm volatile("s_waitcnt vmcnt(1)" ::: "memory");
    } else {
      asm volatile("s_waitcnt vmcnt(4)" ::: "memory");
    }
    __builtin_amdgcn_sched_barrier(0);
    __builtin_amdgcn_s_barrier();        // all waves' loads(h) complete
    __builtin_amdgcn_sched_barrier(0);
    if (h + 1 < NHALF) STAGE(h + 1);     // after barrier: depth-2 is race-free

    const float* buf = ring[h & 1];
    const int row0 = blk0 + h * 16;

    f32x4 acc[4];
#pragma unroll
    for (int cg = 0; cg < 4; ++cg) acc[cg] = (f32x4){0.f, 0.f, 0.f, 0.f};
    f32x4 an0 = (f32x4){0.f, 0.f, 0.f, 0.f};

#pragma unroll
    for (int s = 0; s < 8; ++s) {
      const int k0 = s * 32 + kg * 8;
      s16x8 a0 = frag_from_lds(buf, ln15, k0);
#pragma unroll
      for (int cg = 0; cg < 4; ++cg)
        acc[cg] = __builtin_amdgcn_mfma_f32_16x16x32_bf16(a0, bfr[cg][s], acc[cg], 0, 0, 0);
      if (wave == 3)
        an0 = __builtin_amdgcn_mfma_f32_16x16x32_bf16(a0, bn[s], an0, 0, 0, 0);
    }

    // epilogue: C/D map col = lane&15, row = (lane>>4)*4 + reg  [m89/m91]
    if (wave == 3) {
      // qan: run-length accumulate; atomics only at segment boundaries (rare)
#pragma unroll
      for (int r = 0; r < 4; ++r) {
        int m = kg * 4 + r;
        int g = segid[h * 16 + m];
        if (g != qg) {
#pragma unroll
          for (int cg = 0; cg < 4; ++cg) {
            atomicAdd(&q_a[qg * 64 + cg * 16 + ln15], qpart[cg]);
            qpart[cg] = 0.f;
          }
          qg = g;
        }
#pragma unroll
        for (int cg = 0; cg < 4; ++cg)
          qpart[cg] += acc[cg][r] + bias_c[cg];
      }
      // nl column: C/D frag -> LDS -> one coalesced 64B store
      if (ln15 == 0) {
#pragma unroll
        for (int r = 0; r < 4; ++r) nlbuf[kg * 4 + r] = an0[r];
      }
      if (lane < 16) nl[row0 + lane] = nlbuf[lane];
    } else if (wave == 1 && !nga_is_bf) {
#pragma unroll
      for (int r = 0; r < 4; ++r)
#pragma unroll
        for (int cg = 0; cg < 4; ++cg)
          nga_f32[(size_t)(row0 + kg * 4 + r) * 64 + cg * 16 + ln15] = acc[cg][r] + bias_c[cg];
    } else {
      // transpose through LDS -> 4 coalesced 512B stores
#pragma unroll
      for (int r = 0; r < 4; ++r) {
        int m = kg * 4 + r;
#pragma unroll
        for (int cg = 0; cg < 4; ++cg)
          outbuf[wave][m][cg * 16 + ln15] = f2bf(acc[cg][r] + bias_c[cg]);
      }
      u16* dstp = (wave == 0) ? agn : (wave == 1) ? nga_bf : qna;
#pragma unroll
      for (int j = 0; j < 4; ++j) {
        int li = lane + j * 64;
        int rr = li >> 4, cc = (li & 15) * 4;
        u16x4 v = *reinterpret_cast<const u16x4*>(&outbuf[wave][rr][cc]);
        *reinterpret_cast<u16x4*>(dstp + (size_t)row0 * 64 + (size_t)li * 4) = v;
      }
    }
  }
#undef STAGE

  if (wave == 3) {
#pragma unroll
    for (int cg = 0; cg < 4; ++cg)
      atomicAdd(&q_a[qg * 64 + cg * 16 + ln15], qpart[cg]);
  }
}

// ---------- K2: one block per segment (unchanged) ----------
__global__ __launch_bounds__(1024) void k2_segment(
    const u16* __restrict__ agn, const u16* __restrict__ nga_bf,
    const float* __restrict__ nga_f32, const u16* __restrict__ qna,
    const float* __restrict__ nl, const int* __restrict__ seg_start,
    const void* __restrict__ mask, const int* __restrict__ mkind,
    const float* __restrict__ q_a,
    float* __restrict__ p_a, float* __restrict__ entropy, float* __restrict__ value,
    float* __restrict__ Su, int nga_is_bf) {
  const int g = blockIdx.x;
  const int s = seg_start[g], e = seg_start[g + 1];
  const int n = e - s;
  const int t = threadIdx.x, lane = t & 63, wave = t >> 6;

  __shared__ float wbuf[16];
  __shared__ float cs[16][64], cv[16][64], ci[16][64], cp[16][64];

  float ls = 0.f;
  for (int i = s + t; i < e; i += 1024) ls += __expf(nl[i]);
  ls = wred_sum(ls);
  if (lane == 0) wbuf[wave] = ls;
  __syncthreads();
  float Sn = 0.f;
#pragma unroll
  for (int w = 0; w < 16; ++w) Sn += wbuf[w];
  float invSn = (Sn > 0.f) ? 1.f / Sn : 0.f;

  const int kind = mkind[0];
  const bool mv = mask_at(mask, kind, g * 64 + lane);
  float s_u = 0.f, v_u = 0.f, i_u = 0.f, pa = 0.f;
  for (int i = s + wave; i < e; i += 16) {
    size_t base = (size_t)i * 64 + lane;
    float pn = __expf(nl[i]) * invSn;
    float ev = mv ? __expf(bf2f(agn[base])) : 0.f;
    float rs = wred_sum(ev);
    pa += pn * ((rs > 0.f) ? ev / rs : 0.015625f);
    float y = nga_is_bf ? bf2f(nga_bf[base]) : nga_f32[base];
    float ey = __expf(y);
    s_u += ey;
    v_u += ey * y;
    i_u += ey * bf2f(qna[base]);
  }
  cs[wave][lane] = s_u; cv[wave][lane] = v_u; ci[wave][lane] = i_u;
  cp[wave][lane] = pa;
  __syncthreads();

  if (t < 64) {
    int a = t;
    float S = 0.f, V = 0.f, I = 0.f, P = 0.f;
#pragma unroll
    for (int w = 0; w < 16; ++w) {
      S += cs[w][a]; V += cv[w][a]; I += ci[w][a]; P += cp[w][a];
    }
    p_a[g * 64 + a] = P;
    Su[g * 64 + a] = S;
    float inner = (S > 0.f) ? I / S : 0.f;
    float Q = q_a[g * 64 + a];
    bool mva = mask_at(mask, kind, g * 64 + a);
    float Hn;
    if (n <= 0) Hn = 0.f;
    else if (!mva) Hn = -logf(1.0f / (float)n + EPS_V);
    else Hn = (S > 0.f) ? (logf(S) - V / S) : 0.f;
    float ent_c = -P * logf(P + EPS_V) + P * Hn;
    float val_c = P * (Q + inner);
    ent_c = wred_sum(ent_c);
    val_c = wred_sum(val_c);
    if (a == 0) { entropy[g] = ent_c; value[g] = val_c; }
  }
}

// ---------- K3: logprob (unchanged) ----------
__global__ __launch_bounds__(256) void k3_logprob(
    const float* __restrict__ p_a, const u16* __restrict__ nga_bf,
    const float* __restrict__ nga_f32, const int* __restrict__ indices,
    const int* __restrict__ a_action, const int* __restrict__ a_node,
    const void* __restrict__ mask, const int* __restrict__ mkind,
    const int* __restrict__ n_nodes, const float* __restrict__ Su,
    float* __restrict__ logprob, int G, int nga_is_bf) {
  int g = blockIdx.x * blockDim.x + threadIdx.x;
  if (g >= G) return;
  int kind = mkind[0];
  int a = a_action[g];
  float t1 = logf(p_a[g * 64 + a] + EPS_V);
  int node = a_node[g];
  int g2 = indices[node];
  float p2;
  if (mask_at(mask, kind, g2 * 64 + a)) {
    float S = Su[g2 * 64 + a];
    float y = nga_is_bf ? bf2f(nga_bf[(size_t)node * 64 + a]) : nga_f32[(size_t)node * 64 + a];
    p2 = (S > 0.f) ? __expf(y) / S : 0.f;
  } else {
    p2 = 1.0f / (float)n_nodes[g2];
  }
  logprob[g] = t1 + logf(p2 + EPS_V);
}

// ---------- K4 (bf16): p_n__a = exp(y)/Su ----------
__global__ __launch_bounds__(256) void k4_pna_bf(
    const u16* __restrict__ nga_bf, const int* __restrict__ indices,
    const float* __restrict__ Su, float* __restrict__ pna, int N) {
  int e8 = blockIdx.x * 256 + threadIdx.x;
  if (e8 >= N * 8) return;
  int i = e8 >> 3, a0 = (e8 & 7) * 8;
  int g = indices[i];
  u16x8 y = *reinterpret_cast<const u16x8*>(nga_bf + (size_t)i * 64 + a0);
  float4 S0 = *reinterpret_cast<const float4*>(Su + g * 64 + a0);
  float4 S1 = *reinterpret_cast<const float4*>(Su + g * 64 + a0 + 4);
  float4 o0, o1;
  o0.x = __expf(bf2f(y[0])) / S0.x; o0.y = __expf(bf2f(y[1])) / S0.y;
  o0.z = __expf(bf2f(y[2])) / S0.z; o0.w = __expf(bf2f(y[3])) / S0.w;
  o1.x = __expf(bf2f(y[4])) / S1.x; o1.y = __expf(bf2f(y[5])) / S1.y;
  o1.z = __expf(bf2f(y[6])) / S1.z; o1.w = __expf(bf2f(y[7])) / S1.w;
  float4* dst = reinterpret_cast<float4*>(pna + (size_t)i * 64 + a0);
  dst[0] = o0; dst[1] = o1;
}

// ---------- K4 (f32 fallback, in-place) ----------
__global__ __launch_bounds__(256) void k4_pna_f32(
    float* __restrict__ pna, const int* __restrict__ indices,
    const float* __restrict__ Su, int N) {
  int e4 = blockIdx.x * 256 + threadIdx.x;
  if (e4 >= N * 16) return;
  int i = e4 >> 4, a0 = (e4 & 15) * 4;
  int g = indices[i];
  float4* p = reinterpret_cast<float4*>(pna + (size_t)i * 64 + a0);
  float4 x = *p;
  float4 S = *reinterpret_cast<const float4*>(Su + g * 64 + a0);
  float4 o;
  o.x = __expf(x.x) / S.x; o.y = __expf(x.y) / S.y;
  o.z = __expf(x.z) / S.z; o.w = __expf(x.w) / S.w;
  *p = o;
}

extern "C" void kernel_launch(void* const* d_in, const int* in_sizes, int n_in,
                              void* d_out, int out_size, void* d_ws, size_t ws_size,
                              hipStream_t stream) {
  const float* values = (const float*)d_in[0];
  const int* indices = (const int*)d_in[1];
  const int* a_action = (const int*)d_in[2];
  const int* a_node = (const int*)d_in[3];
  const void* action_mask = d_in[4];
  const int* n_nodes = (const int*)d_in[5];
  const float* w_node = (const float*)d_in[6];
  const float* W_agn = (const float*)d_in[7];
  const float* b_agn = (const float*)d_in[8];
  const float* W_nga = (const float*)d_in[9];
  const float* b_nga = (const float*)d_in[10];
  const float* W_qna = (const float*)d_in[11];
  const float* b_qna = (const float*)d_in[12];
  const float* W_qan = (const float*)d_in[13];
  const float* b_qan = (const float*)d_in[14];

  const int N = in_sizes[1];   // 131072
  const int G = in_sizes[2];   // 256
  const int GA = in_sizes[4];  // G*64

  float* out = (float*)d_out;
  float* o_logprob = out;
  float* o_entropy = out + G;
  float* o_value = out + 2 * G;
  float* o_pa = out + 3 * G;
  float* o_pna = out + 3 * G + GA;

  char* w = (char*)d_ws;
  size_t off = 0;
  u16* agn = (u16*)(w + off); off += (size_t)N * 64 * 2;
  u16* qna = (u16*)(w + off); off += (size_t)N * 64 * 2;
  float* nl = (float*)(w + off); off += (size_t)N * 4;
  float* Su = (float*)(w + off); off += (size_t)GA * 4;
  float* q_a = (float*)(w + off); off += (size_t)GA * 4;
  int* seg_start = (int*)(w + off); off += (size_t)(G + 1) * 4;
  int* mkind = (int*)(w + off); off += 256;
  off = (off + 255) & ~(size_t)255;
  u16* Wpack = (u16*)(w + off); off += (size_t)320 * 256 * 2;
  u16* nga_bf = (u16*)(w + off);
  size_t need_bf = off + (size_t)N * 64 * 2;
  int nga_is_bf = (ws_size >= need_bf) ? 1 : 0;
  float* nga_f32 = o_pna;

  int zero_blocks = (GA + 255) / 256;
  k0_fused<<<2 + 320 + zero_blocks, 256, 0, stream>>>(
      n_nodes, (const unsigned int*)action_mask, w_node, W_agn, W_nga, W_qna, W_qan,
      seg_start, mkind, q_a, Wpack, G, GA / 4);
  k1_gemm<<<N / (NHALF * 16), 256, 0, stream>>>(
      values, Wpack, indices, b_agn, b_nga, b_qna, b_qan,
      agn, nga_bf, nga_f32, qna, q_a, nl, nga_is_bf);
  k2_segment<<<G, 1024, 0, stream>>>(agn, nga_bf, nga_f32, qna, nl, seg_start,
                                     action_mask, mkind, q_a,
                                     o_pa, o_entropy, o_value, Su, nga_is_bf);
  k3_logprob<<<(G + 255) / 256, 256, 0, stream>>>(
      o_pa, nga_bf, nga_f32, indices, a_action, a_node,
      action_mask, mkind, n_nodes, Su, o_logprob, G, nga_is_bf);
  if (nga_is_bf)
    k4_pna_bf<<<(N * 8 + 255) / 256, 256, 0, stream>>>(nga_bf, indices, Su, o_pna, N);
  else
    k4_pna_f32<<<(N * 16 + 255) / 256, 256, 0, stream>>>(o_pna, indices, Su, N);
}

// Round 13
// 120.024 us; speedup vs baseline: 3.3199x; 2.0349x over previous
//
#include <hip/hip_runtime.h>
#include <hip/hip_bf16.h>

typedef unsigned short u16;
typedef unsigned int u32;
typedef __attribute__((ext_vector_type(4))) float f32x4;
typedef __attribute__((ext_vector_type(8))) short s16x8;
typedef __attribute__((ext_vector_type(8))) unsigned short u16x8;
typedef __attribute__((ext_vector_type(4))) unsigned short u16x4;

#define EPS_V (1e-10f)
#define NHALF 8                 // 8 halves x 16 rows = 128 rows per block

__device__ __forceinline__ u16 f2bf(float f) {   // RNE
  unsigned u = __float_as_uint(f);
  u += 0x7fffu + ((u >> 16) & 1u);
  return (u16)(u >> 16);
}
__device__ __forceinline__ float bf2f(u16 h) {
  return __uint_as_float(((unsigned)h) << 16);
}
__device__ __forceinline__ float wred_sum(float v) {
#pragma unroll
  for (int o = 32; o; o >>= 1) v += __shfl_xor(v, o);
  return v;
}
__device__ __forceinline__ bool mask_at(const void* m, int kind, int idx) {
  if (kind == 0) return ((const int*)m)[idx] != 0;
  if (kind == 1) return ((const float*)m)[idx] != 0.0f;
  return ((const unsigned char*)m)[idx] != 0;
}

// ---------- K0 fused prologue (unchanged) ----------
__global__ __launch_bounds__(256) void k0_fused(
    const int* __restrict__ n_nodes, const unsigned int* __restrict__ mask_raw,
    const float* __restrict__ w_node, const float* __restrict__ W_agn,
    const float* __restrict__ W_nga, const float* __restrict__ W_qna,
    const float* __restrict__ W_qan,
    int* __restrict__ seg_start, int* __restrict__ mkind,
    float* __restrict__ q_a, u16* __restrict__ Wpack, int G, int ndw) {
  const int b = blockIdx.x;
  const int t = threadIdx.x;
  if (b == 0) {
    if (t < 64) {
      int base = t * 4;
      int v0 = (base + 0 < G) ? n_nodes[base + 0] : 0;
      int v1 = (base + 1 < G) ? n_nodes[base + 1] : 0;
      int v2 = (base + 2 < G) ? n_nodes[base + 2] : 0;
      int v3 = (base + 3 < G) ? n_nodes[base + 3] : 0;
      int lsum = v0 + v1 + v2 + v3;
      int x = lsum;
#pragma unroll
      for (int o = 1; o < 64; o <<= 1) {
        int y = __shfl_up(x, o);
        if (t >= o) x += y;
      }
      int run = x - lsum;
      if (base + 0 < G) seg_start[base + 0] = run; run += v0;
      if (base + 1 < G) seg_start[base + 1] = run; run += v1;
      if (base + 2 < G) seg_start[base + 2] = run; run += v2;
      if (base + 3 < G) seg_start[base + 3] = run; run += v3;
      if (t == 63) seg_start[G] = run;
    }
  } else if (b == 1) {
    __shared__ int notInt, notFloat;
    if (t == 0) { notInt = 0; notFloat = 0; }
    __syncthreads();
    int li = 0, lf = 0;
    for (int i = t; i < ndw; i += 256) {
      unsigned v = mask_raw[i];
      if (v != 0u && v != 1u) li = 1;
      if (v != 0u && v != 0x3F800000u) lf = 1;
    }
    if (li) atomicOr(&notInt, 1);
    if (lf) atomicOr(&notFloat, 1);
    __syncthreads();
    if (t == 0) mkind[0] = (!notInt) ? 0 : ((!notFloat) ? 1 : 2);
  } else if (b < 2 + 320) {
    int idx = (b - 2) * 256 + t;
    int col = idx >> 8, k = idx & 255;
    float v = 0.f;
    if (col < 64) v = W_agn[col * 256 + k];
    else if (col < 128) v = W_nga[(col - 64) * 256 + k];
    else if (col < 192) v = W_qna[(col - 128) * 256 + k];
    else if (col < 256) v = W_qan[(col - 192) * 256 + k];
    else if (col == 256) v = w_node[k];
    Wpack[idx] = f2bf(v);
  } else {
    int idx = (b - 322) * 256 + t;
    if (idx < G * 64) q_a[idx] = 0.f;
  }
}

// fragment: 8 bf16 of LDS-row m (f32 data), k=k0..k0+7, 16B-granule XOR-(m&7)
__device__ __forceinline__ s16x8 frag_from_lds(const float* Vf, int m, int k0) {
  int g0 = ((k0 >> 2) ^ (m & 7));
  int g1 = g0 ^ 1;
  const f32x4 lo = *reinterpret_cast<const f32x4*>(&Vf[m * 256 + g0 * 4]);
  const f32x4 hi = *reinterpret_cast<const f32x4*>(&Vf[m * 256 + g1 * 4]);
  union { s16x8 v; u32 u[4]; } r;
  r.u[0] = __builtin_amdgcn_perm(__float_as_uint(lo[1]), __float_as_uint(lo[0]), 0x07060302u);
  r.u[1] = __builtin_amdgcn_perm(__float_as_uint(lo[3]), __float_as_uint(lo[2]), 0x07060302u);
  r.u[2] = __builtin_amdgcn_perm(__float_as_uint(hi[1]), __float_as_uint(hi[0]), 0x07060302u);
  r.u[3] = __builtin_amdgcn_perm(__float_as_uint(hi[3]), __float_as_uint(hi[2]), 0x07060302u);
  return r.v;
}

// ---------- K1: ring-pipelined GEMM, 16-row halves, 39.4 KB LDS.
// grid 1024; __launch_bounds__(256,2) -> VGPR cap 256 (NO spill; R12's (256,3)
// capped at ~170 and spilled the 128-VGPR B-frag array -> 4x FETCH).
// 2 resident blocks/CU (8 waves) vs R10's measured ~1 block.
__global__ __launch_bounds__(256, 2) void k1_gemm(
    const float* __restrict__ values, const u16* __restrict__ Wpack,
    const int* __restrict__ indices,
    const float* __restrict__ b_agn, const float* __restrict__ b_nga,
    const float* __restrict__ b_qna, const float* __restrict__ b_qan,
    u16* __restrict__ agn, u16* __restrict__ nga_bf, float* __restrict__ nga_f32,
    u16* __restrict__ qna, float* __restrict__ q_a,
    float* __restrict__ nl, int nga_is_bf) {
  __shared__ float ring[2][16 * 256];   // 32 KB
  __shared__ u16 outbuf[3][16][68];     // 6.4 KB, conflict-free
  __shared__ float nlbuf[16];
  __shared__ int segid[NHALF * 16];

  const int t = threadIdx.x;
  const int lane = t & 63;
  const int wave = t >> 6;              // chunk: 0 agn, 1 nga, 2 qna, 3 qan(+nl)
  const int ln15 = lane & 15;
  const int kg = lane >> 4;
  const int blk0 = blockIdx.x * (NHALF * 16);

  // B fragments for this wave's 64-col chunk (L2-hot), once per block
  s16x8 bfr[4][8];
  {
    const u16* wb = Wpack + (size_t)(wave * 64 + ln15) * 256 + kg * 8;
#pragma unroll
    for (int cg = 0; cg < 4; ++cg)
#pragma unroll
      for (int s = 0; s < 8; ++s)
        bfr[cg][s] = *reinterpret_cast<const s16x8*>(wb + (size_t)(cg * 16) * 256 + s * 32);
  }
  float bias_c[4];
  {
    const float* bp = (wave == 0) ? b_agn : (wave == 1) ? b_nga
                    : (wave == 2) ? b_qna : b_qan;
#pragma unroll
    for (int cg = 0; cg < 4; ++cg) bias_c[cg] = bp[cg * 16 + ln15];
  }
  s16x8 bn[8];
  if (wave == 3) {
    const u16* wb = Wpack + (size_t)(256 + ln15) * 256 + kg * 8;
#pragma unroll
    for (int s = 0; s < 8; ++s)
      bn[s] = *reinterpret_cast<const s16x8*>(wb + s * 32);
#pragma unroll
    for (int j = 0; j < NHALF * 16 / 64; ++j)
      segid[lane + 64 * j] = indices[blk0 + lane + 64 * j];
  }
  float qpart[4] = {0.f, 0.f, 0.f, 0.f};
  int qg = (wave == 3) ? segid[kg * 4] : 0;

#define STAGE(hh)                                                              \
  {                                                                            \
    float* dst_ = ring[(hh) & 1];                                              \
    const int r0_ = blk0 + (hh) * 16;                                          \
    _Pragma("unroll")                                                          \
    for (int i_ = 0; i_ < 4; ++i_) {                                           \
      int m_ = wave * 4 + i_;                                                  \
      const float* gp_ = values + (size_t)(r0_ + m_) * 256 + ((lane ^ (m_ & 7)) << 2); \
      __builtin_amdgcn_global_load_lds(                                        \
          (const __attribute__((address_space(1))) void*)gp_,                  \
          (__attribute__((address_space(3))) void*)&dst_[m_ * 256], 16, 0, 0); \
    }                                                                          \
  }

  STAGE(0);

  for (int h = 0; h < NHALF; ++h) {
    // wait for OWN loads(h); younger ops = stores(h-1) (waves 0-2: 4 b64;
    // wave 3: 1 nl store). h=0: only loads(0) outstanding.
    if (h == 0 || (!nga_is_bf && wave == 1)) {
      asm volatile("s_waitcnt vmcnt(0)" ::: "memory");
    } else if (wave == 3) {
      asm volatile("s_waitcnt vmcnt(1)" ::: "memory");
    } else {
      asm volatile("s_waitcnt vmcnt(4)" ::: "memory");
    }
    __builtin_amdgcn_sched_barrier(0);
    __builtin_amdgcn_s_barrier();        // all waves' loads(h) complete
    __builtin_amdgcn_sched_barrier(0);
    if (h + 1 < NHALF) STAGE(h + 1);     // after barrier: depth-2 is race-free

    const float* buf = ring[h & 1];
    const int row0 = blk0 + h * 16;

    f32x4 acc[4];
#pragma unroll
    for (int cg = 0; cg < 4; ++cg) acc[cg] = (f32x4){0.f, 0.f, 0.f, 0.f};
    f32x4 an0 = (f32x4){0.f, 0.f, 0.f, 0.f};

#pragma unroll
    for (int s = 0; s < 8; ++s) {
      const int k0 = s * 32 + kg * 8;
      s16x8 a0 = frag_from_lds(buf, ln15, k0);
#pragma unroll
      for (int cg = 0; cg < 4; ++cg)
        acc[cg] = __builtin_amdgcn_mfma_f32_16x16x32_bf16(a0, bfr[cg][s], acc[cg], 0, 0, 0);
      if (wave == 3)
        an0 = __builtin_amdgcn_mfma_f32_16x16x32_bf16(a0, bn[s], an0, 0, 0, 0);
    }

    // epilogue: C/D map col = lane&15, row = (lane>>4)*4 + reg  [m89/m91]
    if (wave == 3) {
      // qan: run-length accumulate; atomics only at segment boundaries (rare)
#pragma unroll
      for (int r = 0; r < 4; ++r) {
        int m = kg * 4 + r;
        int g = segid[h * 16 + m];
        if (g != qg) {
#pragma unroll
          for (int cg = 0; cg < 4; ++cg) {
            atomicAdd(&q_a[qg * 64 + cg * 16 + ln15], qpart[cg]);
            qpart[cg] = 0.f;
          }
          qg = g;
        }
#pragma unroll
        for (int cg = 0; cg < 4; ++cg)
          qpart[cg] += acc[cg][r] + bias_c[cg];
      }
      // nl column: C/D frag -> LDS -> one coalesced 64B store
      if (ln15 == 0) {
#pragma unroll
        for (int r = 0; r < 4; ++r) nlbuf[kg * 4 + r] = an0[r];
      }
      if (lane < 16) nl[row0 + lane] = nlbuf[lane];
    } else if (wave == 1 && !nga_is_bf) {
#pragma unroll
      for (int r = 0; r < 4; ++r)
#pragma unroll
        for (int cg = 0; cg < 4; ++cg)
          nga_f32[(size_t)(row0 + kg * 4 + r) * 64 + cg * 16 + ln15] = acc[cg][r] + bias_c[cg];
    } else {
      // transpose through LDS -> 4 coalesced 512B stores
#pragma unroll
      for (int r = 0; r < 4; ++r) {
        int m = kg * 4 + r;
#pragma unroll
        for (int cg = 0; cg < 4; ++cg)
          outbuf[wave][m][cg * 16 + ln15] = f2bf(acc[cg][r] + bias_c[cg]);
      }
      u16* dstp = (wave == 0) ? agn : (wave == 1) ? nga_bf : qna;
#pragma unroll
      for (int j = 0; j < 4; ++j) {
        int li = lane + j * 64;
        int rr = li >> 4, cc = (li & 15) * 4;
        u16x4 v = *reinterpret_cast<const u16x4*>(&outbuf[wave][rr][cc]);
        *reinterpret_cast<u16x4*>(dstp + (size_t)row0 * 64 + (size_t)li * 4) = v;
      }
    }
  }
#undef STAGE

  if (wave == 3) {
#pragma unroll
    for (int cg = 0; cg < 4; ++cg)
      atomicAdd(&q_a[qg * 64 + cg * 16 + ln15], qpart[cg]);
  }
}

// ---------- K2: one block per segment (unchanged) ----------
__global__ __launch_bounds__(1024) void k2_segment(
    const u16* __restrict__ agn, const u16* __restrict__ nga_bf,
    const float* __restrict__ nga_f32, const u16* __restrict__ qna,
    const float* __restrict__ nl, const int* __restrict__ seg_start,
    const void* __restrict__ mask, const int* __restrict__ mkind,
    const float* __restrict__ q_a,
    float* __restrict__ p_a, float* __restrict__ entropy, float* __restrict__ value,
    float* __restrict__ Su, int nga_is_bf) {
  const int g = blockIdx.x;
  const int s = seg_start[g], e = seg_start[g + 1];
  const int n = e - s;
  const int t = threadIdx.x, lane = t & 63, wave = t >> 6;

  __shared__ float wbuf[16];
  __shared__ float cs[16][64], cv[16][64], ci[16][64], cp[16][64];

  float ls = 0.f;
  for (int i = s + t; i < e; i += 1024) ls += __expf(nl[i]);
  ls = wred_sum(ls);
  if (lane == 0) wbuf[wave] = ls;
  __syncthreads();
  float Sn = 0.f;
#pragma unroll
  for (int w = 0; w < 16; ++w) Sn += wbuf[w];
  float invSn = (Sn > 0.f) ? 1.f / Sn : 0.f;

  const int kind = mkind[0];
  const bool mv = mask_at(mask, kind, g * 64 + lane);
  float s_u = 0.f, v_u = 0.f, i_u = 0.f, pa = 0.f;
  for (int i = s + wave; i < e; i += 16) {
    size_t base = (size_t)i * 64 + lane;
    float pn = __expf(nl[i]) * invSn;
    float ev = mv ? __expf(bf2f(agn[base])) : 0.f;
    float rs = wred_sum(ev);
    pa += pn * ((rs > 0.f) ? ev / rs : 0.015625f);
    float y = nga_is_bf ? bf2f(nga_bf[base]) : nga_f32[base];
    float ey = __expf(y);
    s_u += ey;
    v_u += ey * y;
    i_u += ey * bf2f(qna[base]);
  }
  cs[wave][lane] = s_u; cv[wave][lane] = v_u; ci[wave][lane] = i_u;
  cp[wave][lane] = pa;
  __syncthreads();

  if (t < 64) {
    int a = t;
    float S = 0.f, V = 0.f, I = 0.f, P = 0.f;
#pragma unroll
    for (int w = 0; w < 16; ++w) {
      S += cs[w][a]; V += cv[w][a]; I += ci[w][a]; P += cp[w][a];
    }
    p_a[g * 64 + a] = P;
    Su[g * 64 + a] = S;
    float inner = (S > 0.f) ? I / S : 0.f;
    float Q = q_a[g * 64 + a];
    bool mva = mask_at(mask, kind, g * 64 + a);
    float Hn;
    if (n <= 0) Hn = 0.f;
    else if (!mva) Hn = -logf(1.0f / (float)n + EPS_V);
    else Hn = (S > 0.f) ? (logf(S) - V / S) : 0.f;
    float ent_c = -P * logf(P + EPS_V) + P * Hn;
    float val_c = P * (Q + inner);
    ent_c = wred_sum(ent_c);
    val_c = wred_sum(val_c);
    if (a == 0) { entropy[g] = ent_c; value[g] = val_c; }
  }
}

// ---------- K3: logprob (unchanged) ----------
__global__ __launch_bounds__(256) void k3_logprob(
    const float* __restrict__ p_a, const u16* __restrict__ nga_bf,
    const float* __restrict__ nga_f32, const int* __restrict__ indices,
    const int* __restrict__ a_action, const int* __restrict__ a_node,
    const void* __restrict__ mask, const int* __restrict__ mkind,
    const int* __restrict__ n_nodes, const float* __restrict__ Su,
    float* __restrict__ logprob, int G, int nga_is_bf) {
  int g = blockIdx.x * blockDim.x + threadIdx.x;
  if (g >= G) return;
  int kind = mkind[0];
  int a = a_action[g];
  float t1 = logf(p_a[g * 64 + a] + EPS_V);
  int node = a_node[g];
  int g2 = indices[node];
  float p2;
  if (mask_at(mask, kind, g2 * 64 + a)) {
    float S = Su[g2 * 64 + a];
    float y = nga_is_bf ? bf2f(nga_bf[(size_t)node * 64 + a]) : nga_f32[(size_t)node * 64 + a];
    p2 = (S > 0.f) ? __expf(y) / S : 0.f;
  } else {
    p2 = 1.0f / (float)n_nodes[g2];
  }
  logprob[g] = t1 + logf(p2 + EPS_V);
}

// ---------- K4 (bf16): p_n__a = exp(y)/Su ----------
__global__ __launch_bounds__(256) void k4_pna_bf(
    const u16* __restrict__ nga_bf, const int* __restrict__ indices,
    const float* __restrict__ Su, float* __restrict__ pna, int N) {
  int e8 = blockIdx.x * 256 + threadIdx.x;
  if (e8 >= N * 8) return;
  int i = e8 >> 3, a0 = (e8 & 7) * 8;
  int g = indices[i];
  u16x8 y = *reinterpret_cast<const u16x8*>(nga_bf + (size_t)i * 64 + a0);
  float4 S0 = *reinterpret_cast<const float4*>(Su + g * 64 + a0);
  float4 S1 = *reinterpret_cast<const float4*>(Su + g * 64 + a0 + 4);
  float4 o0, o1;
  o0.x = __expf(bf2f(y[0])) / S0.x; o0.y = __expf(bf2f(y[1])) / S0.y;
  o0.z = __expf(bf2f(y[2])) / S0.z; o0.w = __expf(bf2f(y[3])) / S0.w;
  o1.x = __expf(bf2f(y[4])) / S1.x; o1.y = __expf(bf2f(y[5])) / S1.y;
  o1.z = __expf(bf2f(y[6])) / S1.z; o1.w = __expf(bf2f(y[7])) / S1.w;
  float4* dst = reinterpret_cast<float4*>(pna + (size_t)i * 64 + a0);
  dst[0] = o0; dst[1] = o1;
}

// ---------- K4 (f32 fallback, in-place) ----------
__global__ __launch_bounds__(256) void k4_pna_f32(
    float* __restrict__ pna, const int* __restrict__ indices,
    const float* __restrict__ Su, int N) {
  int e4 = blockIdx.x * 256 + threadIdx.x;
  if (e4 >= N * 16) return;
  int i = e4 >> 4, a0 = (e4 & 15) * 4;
  int g = indices[i];
  float4* p = reinterpret_cast<float4*>(pna + (size_t)i * 64 + a0);
  float4 x = *p;
  float4 S = *reinterpret_cast<const float4*>(Su + g * 64 + a0);
  float4 o;
  o.x = __expf(x.x) / S.x; o.y = __expf(x.y) / S.y;
  o.z = __expf(x.z) / S.z; o.w = __expf(x.w) / S.w;
  *p = o;
}

extern "C" void kernel_launch(void* const* d_in, const int* in_sizes, int n_in,
                              void* d_out, int out_size, void* d_ws, size_t ws_size,
                              hipStream_t stream) {
  const float* values = (const float*)d_in[0];
  const int* indices = (const int*)d_in[1];
  const int* a_action = (const int*)d_in[2];
  const int* a_node = (const int*)d_in[3];
  const void* action_mask = d_in[4];
  const int* n_nodes = (const int*)d_in[5];
  const float* w_node = (const float*)d_in[6];
  const float* W_agn = (const float*)d_in[7];
  const float* b_agn = (const float*)d_in[8];
  const float* W_nga = (const float*)d_in[9];
  const float* b_nga = (const float*)d_in[10];
  const float* W_qna = (const float*)d_in[11];
  const float* b_qna = (const float*)d_in[12];
  const float* W_qan = (const float*)d_in[13];
  const float* b_qan = (const float*)d_in[14];

  const int N = in_sizes[1];   // 131072
  const int G = in_sizes[2];   // 256
  const int GA = in_sizes[4];  // G*64

  float* out = (float*)d_out;
  float* o_logprob = out;
  float* o_entropy = out + G;
  float* o_value = out + 2 * G;
  float* o_pa = out + 3 * G;
  float* o_pna = out + 3 * G + GA;

  char* w = (char*)d_ws;
  size_t off = 0;
  u16* agn = (u16*)(w + off); off += (size_t)N * 64 * 2;
  u16* qna = (u16*)(w + off); off += (size_t)N * 64 * 2;
  float* nl = (float*)(w + off); off += (size_t)N * 4;
  float* Su = (float*)(w + off); off += (size_t)GA * 4;
  float* q_a = (float*)(w + off); off += (size_t)GA * 4;
  int* seg_start = (int*)(w + off); off += (size_t)(G + 1) * 4;
  int* mkind = (int*)(w + off); off += 256;
  off = (off + 255) & ~(size_t)255;
  u16* Wpack = (u16*)(w + off); off += (size_t)320 * 256 * 2;
  u16* nga_bf = (u16*)(w + off);
  size_t need_bf = off + (size_t)N * 64 * 2;
  int nga_is_bf = (ws_size >= need_bf) ? 1 : 0;
  float* nga_f32 = o_pna;

  int zero_blocks = (GA + 255) / 256;
  k0_fused<<<2 + 320 + zero_blocks, 256, 0, stream>>>(
      n_nodes, (const unsigned int*)action_mask, w_node, W_agn, W_nga, W_qna, W_qan,
      seg_start, mkind, q_a, Wpack, G, GA / 4);
  k1_gemm<<<N / (NHALF * 16), 256, 0, stream>>>(
      values, Wpack, indices, b_agn, b_nga, b_qna, b_qan,
      agn, nga_bf, nga_f32, qna, q_a, nl, nga_is_bf);
  k2_segment<<<G, 1024, 0, stream>>>(agn, nga_bf, nga_f32, qna, nl, seg_start,
                                     action_mask, mkind, q_a,
                                     o_pa, o_entropy, o_value, Su, nga_is_bf);
  k3_logprob<<<(G + 255) / 256, 256, 0, stream>>>(
      o_pa, nga_bf, nga_f32, indices, a_action, a_node,
      action_mask, mkind, n_nodes, Su, o_logprob, G, nga_is_bf);
  if (nga_is_bf)
    k4_pna_bf<<<(N * 8 + 255) / 256, 256, 0, stream>>>(nga_bf, indices, Su, o_pna, N);
  else
    k4_pna_f32<<<(N * 16 + 255) / 256, 256, 0, stream>>>(o_pna, indices, Su, N);
}